// Round 1
// baseline (2810.362 us; speedup 1.0000x reference)
//
#include <hip/hip_runtime.h>
#include <hip/hip_fp16.h>

// Persistent-kernel autoregressive LSTM for MI355X (gfx950).  Round 6.
//
// R5 post-mortem: window stuck at ~6.3us with all pipes idle -> latency-bound
// on ~3.5 serial IF round-trips per window (drain-before-flag, flag flight +
// detect, fresh-h fetch).  R6 removes the producer's drain RTT:
//  (1) sentinel-verified h loads: all h slots prefilled with 0xFFFFFFFF (two
//      -NaN f16s, never produced by o*tanh(c)); every h read checks its 4
//      dwords and sc0/sc1-reloads on the rare miss.  Data-before-flag ordering
//      no longer needs vmcnt(0) on the producer.
//  (2) publish = one global_store_dwordx2 sc0 sc1 + immediate flag store
//      (no s_waitcnt between) -- the drain migrates to wave0's next barrier,
//      where it overlaps the inter-block flag flight + detect.
//  (3) poll = one global_load_dwordx4 sc0 sc1 per lane (lane i checks flags
//      4i..4i+3), same 16 line-requests/round, 4x fewer instructions.

typedef unsigned short u16;
typedef unsigned int u32;
typedef _Float16 f16;
typedef _Float16 h8 __attribute__((ext_vector_type(8)));
typedef float f4 __attribute__((ext_vector_type(4)));
typedef u32 u32x4 __attribute__((ext_vector_type(4)));
typedef u32 u32x2 __attribute__((ext_vector_type(2)));

#define HSZ 65536  // halves per h slot: layout [128 kgrp][64 b][8 u]
#define SENT 0xFFFFFFFFu

static __device__ __forceinline__ f4 mfma16(h8 a, h8 b, f4 c) {
  return __builtin_amdgcn_mfma_f32_16x16x32_f16(a, b, c, 0, 0, 0);
}

static __device__ __forceinline__ float fsig(float x) {
  return 1.f / (1.f + __expf(-x));
}
// overflow-safe: x->+inf => 1, x->-inf => -1 (no inf/inf NaN)
static __device__ __forceinline__ float ftanh(float x) {
  return 1.f - 2.f / (1.f + __expf(2.f * x));
}

// Verified h load: plain cached 16B load; sentinel dword => producer's store
// not yet visible at IF (or a poisoned stale line) => sc0 sc1 (bypass L1+L2)
// re-read until clean.  Wave-uniform fallback loop, ~never taken.
static __device__ __forceinline__ h8 load_h8v(const u16* hp) {
  union { u32x4 u; h8 h; } cv;
  cv.u = *(const u32x4*)hp;
  int bad = (cv.u.x == SENT) | (cv.u.y == SENT) | (cv.u.z == SENT) | (cv.u.w == SENT);
  if (__builtin_expect(__any(bad), 0)) {
    do {
      u32x4 v;
      asm volatile("global_load_dwordx4 %0, %1, off sc0 sc1"
                   : "=v"(v) : "v"(hp) : "memory");
      __builtin_amdgcn_s_waitcnt(0x0f70);  // vmcnt(0)
      cv.u = v;
      bad = (cv.u.x == SENT) | (cv.u.y == SENT) | (cv.u.z == SENT) | (cv.u.w == SENT);
    } while (__any(bad));
  }
  return cv.h;
}

struct P {
  const u16 *w1h, *weff, *w1x, *w2, *w3, *wdec, *fr;
  const float *br, *ba, *b2s, *b3s, *dec_b;
  u16 *h0, *h1, *h2;
  float* out;
  u32* bar;
};

// A-frag (16x32 tile): lane(q=lane>>4, c=lane&15) holds A[m=c][k=q*8+j].
// h element [b][k] lives at [(k>>3)*512 + b*8 + (k&7)] -> one h8 load.
// Wave (kq, bt2) covers K-quarter kq (8 kt) x batch rows [bt2*32, bt2*32+32).
template<int NJ>
static __device__ __forceinline__ void gemm_hreg(f4* acc, const u16* __restrict__ h,
                                                 const h8 (&wr)[NJ], int kq, int bt2,
                                                 int q, int c) {
#pragma unroll
  for (int jj = 0; jj < NJ; ++jj) {
    int kt = kq * 8 + jj;
    const u16* hp = h + (size_t)(kt * 4 + q) * 512;
    h8 b = wr[jj];
#pragma unroll
    for (int t = 0; t < 2; ++t) {
      h8 a = load_h8v(hp + ((bt2 * 2 + t) * 16 + c) * 8);
      acc[t] = mfma16(a, b, acc[t]);
    }
  }
}

// Same, weights from LDS (w2/w3), kt offset by ktbase.
static __device__ __forceinline__ void gemm_hlds(f4* acc, const u16* __restrict__ h,
                                                 const u16* lw, int ktbase, int kq,
                                                 int bt2, int q, int c, int lane) {
#pragma unroll
  for (int jj = 0; jj < 8; ++jj) {
    int kt = kq * 8 + jj;
    h8 b = *(const h8*)(lw + (size_t)((ktbase + kt) * 64 + lane) * 8);
    const u16* hp = h + (size_t)(kt * 4 + q) * 512;
#pragma unroll
    for (int t = 0; t < 2; ++t) {
      h8 a = load_h8v(hp + ((bt2 * 2 + t) * 16 + c) * 8);
      acc[t] = mfma16(a, b, acc[t]);
    }
  }
}

// Frame input [64][192] row-major; kt in [0,6) mapped kt = kq*2+jj, kq<3.
// Frames are static (never sentinel) -> plain loads.
static __device__ __forceinline__ void gemm_fr(f4* acc, const u16* __restrict__ frt,
                                               const h8 (&wr)[2], int kq, int bt2,
                                               int q, int c) {
  if (kq < 3) {
#pragma unroll
    for (int jj = 0; jj < 2; ++jj) {
      int kt = kq * 2 + jj;
      h8 b = wr[jj];
#pragma unroll
      for (int t = 0; t < 2; ++t) {
        h8 a = *(const h8*)(frt + (size_t)((bt2 * 2 + t) * 16 + c) * 192 + kt * 32 + q * 8);
        acc[t] = mfma16(a, b, acc[t]);
      }
    }
  }
}

__launch_bounds__(512, 2)
__global__ void lstm_main(P p) {
  const int ng = blockIdx.x;        // unit-group: owns hidden units [4ng, 4ng+4)
  const int tid = threadIdx.x;
  const int lane = tid & 63;
  const int w = tid >> 6;           // 8 waves
  const int kq = w & 3;             // K-quarter
  const int bt2 = w >> 2;           // batch half
  const int c = lane & 15;
  const int q = lane >> 4;

  __shared__ u16 lds_w2[64 * 512];       // 64 KB  [kt][lane][8] B-frags
  __shared__ u16 lds_w3[64 * 512];       // 64 KB
  __shared__ float part[4 * 64 * 17];    // [kq][brow][c pad17]
  __shared__ float decp[8][64];

  // ---- one-time: stage w2/w3 slices into LDS ----
  {
    const uint4* s2 = (const uint4*)(p.w2 + (size_t)ng * 64 * 512);
    const uint4* s3 = (const uint4*)(p.w3 + (size_t)ng * 64 * 512);
    uint4* d2 = (uint4*)lds_w2;
    uint4* d3 = (uint4*)lds_w3;
    for (int i = tid; i < 4096; i += 512) { d2[i] = s2[i]; d3[i] = s3[i]; }
  }

  // ---- one-time: w1h/weff/w1x B-frags into registers (~72 VGPR/wave) ----
  h8 r_w1h[8], r_weff[8], r_w1x[2];
  {
#pragma unroll
    for (int jj = 0; jj < 8; ++jj) {
      r_w1h[jj] = *(const h8*)(p.w1h + (size_t)((ng * 32 + kq * 8 + jj) * 64 + lane) * 8);
      r_weff[jj] = *(const h8*)(p.weff + (size_t)((ng * 32 + kq * 8 + jj) * 64 + lane) * 8);
    }
    if (kq < 3) {
#pragma unroll
      for (int jj = 0; jj < 2; ++jj)
        r_w1x[jj] = *(const h8*)(p.w1x + (size_t)((ng * 6 + kq * 2 + jj) * 64 + lane) * 8);
    }
  }

  // ---- wave-0-only: hoist the 4x16 bias vectors into registers ----
  float rb_r[16], rb_a[16], rb2[16], rb3[16];
  if (w == 0) {
#pragma unroll
    for (int i = 0; i < 16; ++i) {
      int idx = (i >> 2) * 1024 + ng * 4 + (i & 3);
      rb_r[i] = p.br[idx];  rb_a[i] = p.ba[idx];
      rb2[i] = p.b2s[idx];  rb3[i] = p.b3s[idx];
    }
  }
  const float dec_bng = (ng < 171) ? p.dec_b[ng] : 0.f;
  __syncthreads();

  // c-state: wave 0, lane = batch row, 4 units per layer
  float cr0[4] = {0, 0, 0, 0}, cr1[4] = {0, 0, 0, 0}, cr2[4] = {0, 0, 0, 0};
  u32 pub = 0;  // publishes completed (uniform across all threads)

  // wave 0 only: reduce K-partials, nonlin, c-state, h-store, publish.
  // R6: NO drain between data and flag -- consumers sentinel-verify the data.
  auto combine_pub = [&](float* crL, const float* rb, u16* hw) {
    u32 pk0 = 0, pk1 = 0;
#pragma unroll
    for (int u = 0; u < 4; ++u) {
      float s0 = rb[0 + u], s1 = rb[4 + u], s2 = rb[8 + u], s3 = rb[12 + u];
#pragma unroll
      for (int kqi = 0; kqi < 4; ++kqi) {
        const float* pp = &part[(kqi * 64 + lane) * 17 + u];
        s0 += pp[0]; s1 += pp[4]; s2 += pp[8]; s3 += pp[12];
      }
      float iv = fsig(s0), fv = fsig(s1), gv = ftanh(s2), ov = fsig(s3);
      float cn = fv * crL[u] + iv * gv;
      crL[u] = cn;
      f16 hh = (f16)(ov * ftanh(cn));
      u32 bits = (u32)*(const u16*)&hh;
      if (u < 2) pk0 |= bits << (16 * u); else pk1 |= bits << (16 * (u - 2));
    }
    // h[b][4ng+u]: u32 base (ng>>1)*256 + b*4 + (ng&1)*2; one 8B store.
    u32* dst = (u32*)hw + (size_t)(ng >> 1) * 256 + lane * 4 + (ng & 1) * 2;
    u32x2 pk; pk.x = pk0; pk.y = pk1;
    asm volatile("global_store_dwordx2 %0, %1, off sc0 sc1"
                 : : "v"(dst), "v"(pk) : "memory");
    if (lane == 0) {
      u32* fl = p.bar + ng;
      asm volatile("global_store_dword %0, %1, off sc0 sc1"
                   : : "v"(fl), "v"(pub) : "memory");
    }
  };

  // wave 0 polls all 256 slots for >= pub (lane i covers flags 4i..4i+3 via
  // one sc-bypass dwordx4); other waves park at the barrier.
  auto waitall = [&]() {
    if (w == 0) {
      const u32* fp = p.bar + lane * 4;
      for (;;) {
        u32x4 v;
        asm volatile("global_load_dwordx4 %0, %1, off sc0 sc1"
                     : "=v"(v) : "v"(fp) : "memory");
        __builtin_amdgcn_s_waitcnt(0x0f70);  // vmcnt(0)
        u32 m01 = v.x < v.y ? v.x : v.y;
        u32 m23 = v.z < v.w ? v.z : v.w;
        u32 mn = m01 < m23 ? m01 : m23;
        if (__all((int)(mn >= pub))) break;
      }
    }
    __syncthreads();
  };

  auto put_part = [&](const f4* acc) {
#pragma unroll
    for (int t = 0; t < 2; ++t)
#pragma unroll
      for (int r = 0; r < 4; ++r)
        part[(kq * 64 + bt2 * 32 + t * 16 + q * 4 + r) * 17 + c] = acc[t][r];
  };

  auto dec_partial = [&](const u16* __restrict__ h2b) {
    if (ng < 171) {
      const u16* hp = h2b + (size_t)w * 16 * 512 + lane * 8;
      const u16* wp = p.wdec + (size_t)ng * 1024 + w * 128;
      float s = 0.f;
#pragma unroll 4
      for (int i = 0; i < 16; ++i) {
        h8 hv = load_h8v(hp + (size_t)i * 512);
        h8 wv8 = *(const h8*)(wp + i * 8);
#pragma unroll
        for (int jj = 0; jj < 8; ++jj) s += (float)hv[jj] * (float)wv8[jj];
      }
      decp[w][lane] = s;
    }
  };
  auto dec_reduce = [&](int tout) {  // one wave, lane = batch row
    if (ng < 171) {
      float o = dec_bng;
#pragma unroll
      for (int i = 0; i < 8; ++i) o += decp[i][lane];
      p.out[(size_t)lane * 17100 + (size_t)tout * 171 + ng] = o;
    }
  };

  for (int t = 0; t < 100; ++t) {
    const bool cond = (t % 10) < 5;
    const u16* h0r = p.h0 + (size_t)t * HSZ;  // slot 0 = zeros
    const u16* h1r = p.h1 + (size_t)t * HSZ;
    const u16* h2r = p.h2 + (size_t)t * HSZ;
    u16* h0w = p.h0 + (size_t)(t + 1) * HSZ;
    u16* h1w = p.h1 + (size_t)(t + 1) * HSZ;
    u16* h2w = p.h2 + (size_t)(t + 1) * HSZ;

    // ---- window A: layer 1 ----
    {
      f4 acc[2] = {{0, 0, 0, 0}, {0, 0, 0, 0}};
      gemm_hreg<8>(acc, h0r, r_w1h, kq, bt2, q, c);   // stale (certified)
      if (cond) {
        gemm_fr(acc, p.fr + (size_t)t * 64 * 192, r_w1x, kq, bt2, q, c);
        __syncthreads();   // rendezvous only: no fresh operand, skip grid wait
      } else {
        waitall();                                    // h2(t-1) publishes
        gemm_hreg<8>(acc, h2r, r_weff, kq, bt2, q, c);
      }
      put_part(acc);
      __syncthreads();
      ++pub;
      if (w == 0) combine_pub(cr0, cond ? rb_r : rb_a, h0w);
    }
    // ---- window B: layer 2 ----
    {
      f4 acc[2] = {{0, 0, 0, 0}, {0, 0, 0, 0}};
      gemm_hlds(acc, h1r, lds_w2, 32, kq, bt2, q, c, lane);  // stale hh-half
      waitall();                                             // h0(t) publishes
      gemm_hlds(acc, h0w, lds_w2, 0, kq, bt2, q, c, lane);   // fresh ih-half
      put_part(acc);
      __syncthreads();
      ++pub;
      if (w == 0) combine_pub(cr1, rb2, h1w);
    }
    // ---- window C: layer 3 (+ decoder for t-1, stale h2) ----
    {
      f4 acc[2] = {{0, 0, 0, 0}, {0, 0, 0, 0}};
      gemm_hlds(acc, h2r, lds_w3, 32, kq, bt2, q, c, lane);  // stale hh-half
      if (t > 0) dec_partial(h2r);                           // stale (certified)
      waitall();                                             // h1(t) publishes
      gemm_hlds(acc, h1w, lds_w3, 0, kq, bt2, q, c, lane);   // fresh ih-half
      put_part(acc);
      __syncthreads();
      ++pub;
      if (w == 0) combine_pub(cr2, rb3, h2w);
      else if (w == 1 && t > 0) dec_reduce(t - 1);
    }
  }
  // final decoder: out(99) from h2 slot 100
  waitall();
  dec_partial(p.h2 + (size_t)100 * HSZ);
  __syncthreads();
  if (w == 0) dec_reduce(99);
}

// ------------------------- prep kernels -------------------------

// Pack [4096 x (KA+KB)] fp32 weights (two halves) into MFMA-B fragments:
// dst[((ng*nkt + kt)*64 + lane)*8 + j] = W[row(c)][kt*32 + (lane>>4)*8 + j]
// row(c) = (c>>2)*1024 + ng*4 + (c&3).  Zero-pads k >= KA+KB.
__global__ void pack_w_kernel(const float* __restrict__ srcA, int KA,
                              const float* __restrict__ srcB, int KB,
                              u16* __restrict__ dst, int nkt) {
  int blk = blockIdx.x;
  int ng = blk / nkt, kt = blk % nkt;
  int lane = threadIdx.x;
  int c = lane & 15, q = lane >> 4;
  int row = (c >> 2) * 1024 + ng * 4 + (c & 3);
  int k0 = kt * 32 + q * 8;
  alignas(16) u16 outv[8];
  for (int j = 0; j < 8; ++j) {
    int k = k0 + j;
    float v = 0.f;
    if (k < KA) v = srcA[(size_t)row * KA + k];
    else if (k - KA < KB) v = srcB[(size_t)row * KB + (k - KA)];
    f16 hv = (f16)v;
    outv[j] = *(u16*)&hv;
  }
  *(uint4*)(dst + ((size_t)blk * 64 + lane) * 8) = *(const uint4*)outv;
}

// W_eff[n][k] = sum_{r<171} w_ih1[n][r] * dec_w[r][k], MFMA-B packed fp16.
__global__ void pack_weff_kernel(const float* __restrict__ w_ih1,
                                 const float* __restrict__ dec_w, u16* __restrict__ dst) {
  int blk = blockIdx.x;  // ng*32 + kt
  int ng = blk >> 5, kt = blk & 31;
  int lane = threadIdx.x;
  int c = lane & 15, q = lane >> 4;
  int row = (c >> 2) * 1024 + ng * 4 + (c & 3);
  int k0 = kt * 32 + q * 8;
  float acc[8] = {0.f, 0.f, 0.f, 0.f, 0.f, 0.f, 0.f, 0.f};
  for (int r = 0; r < 171; ++r) {
    float wi = w_ih1[(size_t)row * 171 + r];
    const float* dw = dec_w + (size_t)r * 1024 + k0;
#pragma unroll
    for (int j = 0; j < 8; ++j) acc[j] += wi * dw[j];
  }
  alignas(16) u16 outv[8];
  for (int j = 0; j < 8; ++j) { f16 hv = (f16)acc[j]; outv[j] = *(u16*)&hv; }
  *(uint4*)(dst + ((size_t)blk * 64 + lane) * 8) = *(const uint4*)outv;
}

__global__ void prep_bias_kernel(const float* b_ih1, const float* b_hh1,
                                 const float* w_ih1, const float* dec_b,
                                 const float* b_ih2, const float* b_hh2,
                                 const float* b_ih3, const float* b_hh3,
                                 float* br, float* ba, float* b2, float* b3) {
  int n = blockIdx.x * 256 + threadIdx.x;  // 0..4095
  float s = b_ih1[n] + b_hh1[n];
  br[n] = s;
  float a = 0.f;
  for (int r = 0; r < 171; ++r) a += w_ih1[(size_t)n * 171 + r] * dec_b[r];
  ba[n] = s + a;  // autoregressive path: + W_ih1 @ dec_b
  b2[n] = b_ih2[n] + b_hh2[n];
  b3[n] = b_ih3[n] + b_hh3[n];
}

// real_seq [64][100][171] fp32 -> fr16 [100][64][192] fp16 (zero-padded K)
__global__ void pack_frames_kernel(const float* __restrict__ rs, u16* __restrict__ fr) {
  int i = blockIdx.x * 256 + threadIdx.x;
  int j = i % 192;
  int tb = i / 192;
  int b = tb % 64, t = tb / 64;
  float v = (j < 171) ? rs[((size_t)b * 100 + t) * 171 + j] : 0.f;
  f16 hv = (f16)v;
  fr[i] = *(u16*)&hv;
}

__global__ void pack_wdec_kernel(const float* __restrict__ dw, u16* __restrict__ dst) {
  int i = blockIdx.x * 256 + threadIdx.x;
  if (i < 171 * 1024) { f16 hv = (f16)dw[i]; dst[i] = *(u16*)&hv; }
}

// R6: h slot 0 = real zeros (initial state, valid data); slots 1..100 =
// sentinel 0xFFFFFFFF (consumers verify-read).  Also zero the barrier page.
__global__ void init_kernel(u32* h0, u32* h1, u32* h2, u32* bar) {
  int i = blockIdx.x * 256 + threadIdx.x;   // 0 .. 101*32768-1
  const int SLOT = 32768;                   // u32 per h slot
  u32 v = (i < SLOT) ? 0u : SENT;
  h0[i] = v; h1[i] = v; h2[i] = v;
  if (i < 2048) bar[i] = 0;
}

extern "C" void kernel_launch(void* const* d_in, const int* in_sizes, int n_in,
                              void* d_out, int out_size, void* d_ws, size_t ws_size,
                              hipStream_t stream) {
  const float* real_seq = (const float*)d_in[0];
  const float* w_ih1 = (const float*)d_in[1];
  const float* w_hh1 = (const float*)d_in[2];
  const float* b_ih1 = (const float*)d_in[3];
  const float* b_hh1 = (const float*)d_in[4];
  const float* w_ih2 = (const float*)d_in[5];
  const float* w_hh2 = (const float*)d_in[6];
  const float* b_ih2 = (const float*)d_in[7];
  const float* b_hh2 = (const float*)d_in[8];
  const float* w_ih3 = (const float*)d_in[9];
  const float* w_hh3 = (const float*)d_in[10];
  const float* b_ih3 = (const float*)d_in[11];
  const float* b_hh3 = (const float*)d_in[12];
  const float* dec_w = (const float*)d_in[13];
  const float* dec_b = (const float*)d_in[14];

  char* ws = (char*)d_ws;
  size_t off = 0;
  auto alloc = [&](size_t bytes) {
    char* pp = ws + off;
    off += (bytes + 255) & ~(size_t)255;
    return pp;
  };
  u16* w1h  = (u16*)alloc(256ULL * 32 * 512 * 2);   // w_hh1 packed
  u16* weff = (u16*)alloc(256ULL * 32 * 512 * 2);   // W_ih1 @ dec_w packed
  u16* w1x  = (u16*)alloc(256ULL * 6 * 512 * 2);    // w_ih1 packed (K padded 192)
  u16* w2   = (u16*)alloc(256ULL * 64 * 512 * 2);   // [w_ih2 | w_hh2] packed
  u16* w3   = (u16*)alloc(256ULL * 64 * 512 * 2);   // [w_ih3 | w_hh3] packed
  u16* wdec = (u16*)alloc(171ULL * 1024 * 2);       // dec_w fp16 row-major
  u16* fr   = (u16*)alloc(100ULL * 64 * 192 * 2);   // frames fp16 padded
  u16* h0   = (u16*)alloc(101ULL * HSZ * 2);        // rotating h, [k/8][b][8]
  u16* h1   = (u16*)alloc(101ULL * HSZ * 2);
  u16* h2   = (u16*)alloc(101ULL * HSZ * 2);
  float* br  = (float*)alloc(4096 * 4);
  float* ba  = (float*)alloc(4096 * 4);
  float* b2s = (float*)alloc(4096 * 4);
  float* b3s = (float*)alloc(4096 * 4);
  u32* bar   = (u32*)alloc(8192);
  (void)ws_size; (void)in_sizes; (void)n_in; (void)out_size;  // needs ~91 MiB ws

  pack_w_kernel<<<256 * 32, 64, 0, stream>>>(w_hh1, 1024, nullptr, 0, w1h, 32);
  pack_w_kernel<<<256 * 6, 64, 0, stream>>>(w_ih1, 171, nullptr, 0, w1x, 6);
  pack_w_kernel<<<256 * 64, 64, 0, stream>>>(w_ih2, 1024, w_hh2, 1024, w2, 64);
  pack_w_kernel<<<256 * 64, 64, 0, stream>>>(w_ih3, 1024, w_hh3, 1024, w3, 64);
  pack_weff_kernel<<<256 * 32, 64, 0, stream>>>(w_ih1, dec_w, weff);
  pack_wdec_kernel<<<(171 * 1024 + 255) / 256, 256, 0, stream>>>(dec_w, wdec);
  pack_frames_kernel<<<100 * 64 * 192 / 256, 256, 0, stream>>>(real_seq, fr);
  prep_bias_kernel<<<16, 256, 0, stream>>>(b_ih1, b_hh1, w_ih1, dec_b,
                                           b_ih2, b_hh2, b_ih3, b_hh3, br, ba, b2s, b3s);
  init_kernel<<<101 * 32768 / 256, 256, 0, stream>>>((u32*)h0, (u32*)h1, (u32*)h2, bar);

  P p{w1h, weff, w1x, w2, w3, wdec, fr, br, ba, b2s, b3s, dec_b,
      h0, h1, h2, (float*)d_out, bar};
  lstm_main<<<256, 512, 0, stream>>>(p);
}

// Round 2
// 1754.440 us; speedup vs baseline: 1.6019x; 1.6019x over previous
//
#include <hip/hip_runtime.h>
#include <hip/hip_fp16.h>

// Persistent-kernel autoregressive LSTM for MI355X (gfx950).  Round 7.
//
// R6 post-mortem: per-load sentinel verify broke the 16-load pipeline
// (serialized miss latencies) and flag-vs-data races left stale-sentinel
// lines in consumer L2s that re-triggered fallbacks for the slot lifetime
// (1794 -> 2571us).  R7 keeps the drain-removal goal but fixes both:
//  (1) canary-gated publish: producer stores ONLY data (sc0sc1, no drain,
//      no flag).  The consumer's designated wave (wave 1) bypass-polls one
//      16B canary per 1KB producer region (128 regions) of the exact slot
//      it needs -- the data IS the flag, so ordering is free.  Plain reads
//      start only after canary detect => races confined to intra-burst skew.
//  (2) grouped verify: each gemm issues all 16 plain loads, then ONE check
//      over the 16 fragments, with a rarely-taken whole-group sc0sc1 retry.
//      Load pipelining is preserved; the check is ~80 VALU ops.
//  (3) polling on wave 1 overlaps wave 0's combine; combine is now short
//      (no vmcnt(0) drain) so wave 0 rejoins the gemm quickly.

typedef unsigned short u16;
typedef unsigned int u32;
typedef _Float16 f16;
typedef _Float16 h8 __attribute__((ext_vector_type(8)));
typedef float f4 __attribute__((ext_vector_type(4)));
typedef u32 u32x4 __attribute__((ext_vector_type(4)));
typedef u32 u32x2 __attribute__((ext_vector_type(2)));

#define HSZ 65536  // halves per h slot: layout [128 kgrp][64 b][8 u]
#define SENT 0xFFFFFFFFu

static __device__ __forceinline__ f4 mfma16(h8 a, h8 b, f4 c) {
  return __builtin_amdgcn_mfma_f32_16x16x32_f16(a, b, c, 0, 0, 0);
}

static __device__ __forceinline__ float fsig(float x) {
  return 1.f / (1.f + __expf(-x));
}
// overflow-safe: x->+inf => 1, x->-inf => -1 (no inf/inf NaN)
static __device__ __forceinline__ float ftanh(float x) {
  return 1.f - 2.f / (1.f + __expf(2.f * x));
}

// max of the 4 dwords of a fragment: == SENT iff any dword is the sentinel.
static __device__ __forceinline__ u32 sentmax(h8 v) {
  union { h8 h; u32x4 u; } cv; cv.h = v;
  u32 a = cv.u.x > cv.u.y ? cv.u.x : cv.u.y;
  u32 b = cv.u.z > cv.u.w ? cv.u.z : cv.u.w;
  return a > b ? a : b;
}

static __device__ __forceinline__ h8 bypass_load(const u16* p) {
  u32x4 v;
  asm volatile("global_load_dwordx4 %0, %1, off sc0 sc1"
               : "=v"(v) : "v"(p) : "memory");
  union { u32x4 u; h8 h; } cv; cv.u = v;
  return cv.h;
}

struct P {
  const u16 *w1h, *weff, *w1x, *w2, *w3, *wdec, *fr;
  const float *br, *ba, *b2s, *b3s, *dec_b;
  u16 *h0, *h1, *h2;
  float* out;
};

// A-frag (16x32 tile): lane(q=lane>>4, c=lane&15) holds A[m=c][k=q*8+j].
// h element [b][k] lives at [(k>>3)*512 + b*8 + (k&7)] -> one h8 load.
// Wave (kq, bt2) covers K-quarter kq (8 kt) x batch rows [bt2*32, bt2*32+32).
// Grouped verify: 16 plain loads -> one sentinel check -> rare bypass retry.
template<int NJ>
static __device__ __forceinline__ void gemm_hreg(f4* acc, const u16* __restrict__ h,
                                                 const h8 (&wr)[NJ], int kq, int bt2,
                                                 int q, int c) {
  h8 a[NJ * 2];
#pragma unroll
  for (int jj = 0; jj < NJ; ++jj) {
    const u16* hp = h + (size_t)((kq * 8 + jj) * 4 + q) * 512;
#pragma unroll
    for (int t = 0; t < 2; ++t)
      a[jj * 2 + t] = *(const h8*)(hp + ((bt2 * 2 + t) * 16 + c) * 8);
  }
  u32 mx = 0;
#pragma unroll
  for (int i = 0; i < NJ * 2; ++i) { u32 s = sentmax(a[i]); mx = mx > s ? mx : s; }
  if (__builtin_expect(__any((int)(mx == SENT)), 0)) {
    for (;;) {
#pragma unroll
      for (int jj = 0; jj < NJ; ++jj) {
        const u16* hp = h + (size_t)((kq * 8 + jj) * 4 + q) * 512;
#pragma unroll
        for (int t = 0; t < 2; ++t)
          a[jj * 2 + t] = bypass_load(hp + ((bt2 * 2 + t) * 16 + c) * 8);
      }
      __builtin_amdgcn_s_waitcnt(0x0f70);  // vmcnt(0)
      mx = 0;
#pragma unroll
      for (int i = 0; i < NJ * 2; ++i) { u32 s = sentmax(a[i]); mx = mx > s ? mx : s; }
      if (!__any((int)(mx == SENT))) break;
    }
  }
#pragma unroll
  for (int jj = 0; jj < NJ; ++jj)
#pragma unroll
    for (int t = 0; t < 2; ++t)
      acc[t] = mfma16(a[jj * 2 + t], wr[jj], acc[t]);
}

// Same, weights from LDS (w2/w3), kt offset by ktbase.
static __device__ __forceinline__ void gemm_hlds(f4* acc, const u16* __restrict__ h,
                                                 const u16* lw, int ktbase, int kq,
                                                 int bt2, int q, int c, int lane) {
  h8 a[16];
#pragma unroll
  for (int jj = 0; jj < 8; ++jj) {
    const u16* hp = h + (size_t)((kq * 8 + jj) * 4 + q) * 512;
#pragma unroll
    for (int t = 0; t < 2; ++t)
      a[jj * 2 + t] = *(const h8*)(hp + ((bt2 * 2 + t) * 16 + c) * 8);
  }
  u32 mx = 0;
#pragma unroll
  for (int i = 0; i < 16; ++i) { u32 s = sentmax(a[i]); mx = mx > s ? mx : s; }
  if (__builtin_expect(__any((int)(mx == SENT)), 0)) {
    for (;;) {
#pragma unroll
      for (int jj = 0; jj < 8; ++jj) {
        const u16* hp = h + (size_t)((kq * 8 + jj) * 4 + q) * 512;
#pragma unroll
        for (int t = 0; t < 2; ++t)
          a[jj * 2 + t] = bypass_load(hp + ((bt2 * 2 + t) * 16 + c) * 8);
      }
      __builtin_amdgcn_s_waitcnt(0x0f70);
      mx = 0;
#pragma unroll
      for (int i = 0; i < 16; ++i) { u32 s = sentmax(a[i]); mx = mx > s ? mx : s; }
      if (!__any((int)(mx == SENT))) break;
    }
  }
#pragma unroll
  for (int jj = 0; jj < 8; ++jj) {
    h8 b = *(const h8*)(lw + (size_t)((ktbase + kq * 8 + jj) * 64 + lane) * 8);
    acc[0] = mfma16(a[jj * 2 + 0], b, acc[0]);
    acc[1] = mfma16(a[jj * 2 + 1], b, acc[1]);
  }
}

// Frame input [64][192] row-major; kt in [0,6) mapped kt = kq*2+jj, kq<3.
// Frames are static (never sentinel) -> plain loads, no verify.
static __device__ __forceinline__ void gemm_fr(f4* acc, const u16* __restrict__ frt,
                                               const h8 (&wr)[2], int kq, int bt2,
                                               int q, int c) {
  if (kq < 3) {
#pragma unroll
    for (int jj = 0; jj < 2; ++jj) {
      int kt = kq * 2 + jj;
      h8 b = wr[jj];
#pragma unroll
      for (int t = 0; t < 2; ++t) {
        h8 a = *(const h8*)(frt + (size_t)((bt2 * 2 + t) * 16 + c) * 192 + kt * 32 + q * 8);
        acc[t] = mfma16(a, b, acc[t]);
      }
    }
  }
}

__launch_bounds__(512, 2)
__global__ void lstm_main(P p) {
  const int ng = blockIdx.x;        // unit-group: owns hidden units [4ng, 4ng+4)
  const int tid = threadIdx.x;
  const int lane = tid & 63;
  const int w = tid >> 6;           // 8 waves
  const int kq = w & 3;             // K-quarter
  const int bt2 = w >> 2;           // batch half
  const int c = lane & 15;
  const int q = lane >> 4;

  __shared__ u16 lds_w2[64 * 512];       // 64 KB  [kt][lane][8] B-frags
  __shared__ u16 lds_w3[64 * 512];       // 64 KB
  __shared__ float part[4 * 64 * 17];    // [kq][brow][c pad17]
  __shared__ float decp[8][64];

  // ---- one-time: stage w2/w3 slices into LDS ----
  {
    const uint4* s2 = (const uint4*)(p.w2 + (size_t)ng * 64 * 512);
    const uint4* s3 = (const uint4*)(p.w3 + (size_t)ng * 64 * 512);
    uint4* d2 = (uint4*)lds_w2;
    uint4* d3 = (uint4*)lds_w3;
    for (int i = tid; i < 4096; i += 512) { d2[i] = s2[i]; d3[i] = s3[i]; }
  }

  // ---- one-time: w1h/weff/w1x B-frags into registers (~72 VGPR/wave) ----
  h8 r_w1h[8], r_weff[8], r_w1x[2];
  {
#pragma unroll
    for (int jj = 0; jj < 8; ++jj) {
      r_w1h[jj] = *(const h8*)(p.w1h + (size_t)((ng * 32 + kq * 8 + jj) * 64 + lane) * 8);
      r_weff[jj] = *(const h8*)(p.weff + (size_t)((ng * 32 + kq * 8 + jj) * 64 + lane) * 8);
    }
    if (kq < 3) {
#pragma unroll
      for (int jj = 0; jj < 2; ++jj)
        r_w1x[jj] = *(const h8*)(p.w1x + (size_t)((ng * 6 + kq * 2 + jj) * 64 + lane) * 8);
    }
  }

  // ---- wave-0-only: hoist the 4x16 bias vectors into registers ----
  float rb_r[16], rb_a[16], rb2[16], rb3[16];
  if (w == 0) {
#pragma unroll
    for (int i = 0; i < 16; ++i) {
      int idx = (i >> 2) * 1024 + ng * 4 + (i & 3);
      rb_r[i] = p.br[idx];  rb_a[i] = p.ba[idx];
      rb2[i] = p.b2s[idx];  rb3[i] = p.b3s[idx];
    }
  }
  const float dec_bng = (ng < 171) ? p.dec_b[ng] : 0.f;
  __syncthreads();

  // c-state: wave 0, lane = batch row, 4 units per layer
  float cr0[4] = {0, 0, 0, 0}, cr1[4] = {0, 0, 0, 0}, cr2[4] = {0, 0, 0, 0};

  // wave 0 only: reduce K-partials, nonlin, c-state, publish DATA ONLY
  // (one sc0sc1 dwordx2 per lane; no drain, no flag -- canaries gate readers).
  auto combine_pub = [&](float* crL, const float* rb, u16* hw) {
    u32 pk0 = 0, pk1 = 0;
#pragma unroll
    for (int u = 0; u < 4; ++u) {
      float s0 = rb[0 + u], s1 = rb[4 + u], s2 = rb[8 + u], s3 = rb[12 + u];
#pragma unroll
      for (int kqi = 0; kqi < 4; ++kqi) {
        const float* pp = &part[(kqi * 64 + lane) * 17 + u];
        s0 += pp[0]; s1 += pp[4]; s2 += pp[8]; s3 += pp[12];
      }
      float iv = fsig(s0), fv = fsig(s1), gv = ftanh(s2), ov = fsig(s3);
      float cn = fv * crL[u] + iv * gv;
      crL[u] = cn;
      f16 hh = (f16)(ov * ftanh(cn));
      u32 bits = (u32)*(const u16*)&hh;
      if (u < 2) pk0 |= bits << (16 * u); else pk1 |= bits << (16 * (u - 2));
    }
    // h[b][4ng+u]: u32 base (ng>>1)*256 + b*4 + (ng&1)*2; one 8B store.
    u32* dst = (u32*)hw + (size_t)(ng >> 1) * 256 + lane * 4 + (ng & 1) * 2;
    u32x2 pk; pk.x = pk0; pk.y = pk1;
    asm volatile("global_store_dwordx2 %0, %1, off sc0 sc1"
                 : : "v"(dst), "v"(pk) : "memory");
  };

  // wave 1 bypass-polls one 16B canary (batch-row-0 units) per 1KB region of
  // the slot (128 regions; lane covers 2).  Data arrival IS the publish signal.
  auto canary_wait = [&](const u16* slot) {
    if (w == 1) {
      const u32* cp = (const u32*)slot + (size_t)lane * 512;
      for (;;) {
        u32x4 v0, v1;
        asm volatile("global_load_dwordx4 %0, %2, off sc0 sc1\n\t"
                     "global_load_dwordx4 %1, %3, off sc0 sc1"
                     : "=v"(v0), "=v"(v1) : "v"(cp), "v"(cp + 256) : "memory");
        __builtin_amdgcn_s_waitcnt(0x0f70);  // vmcnt(0)
        u32 a0 = v0.x > v0.y ? v0.x : v0.y;
        u32 a1 = v0.z > v0.w ? v0.z : v0.w;
        u32 a2 = v1.x > v1.y ? v1.x : v1.y;
        u32 a3 = v1.z > v1.w ? v1.z : v1.w;
        u32 m01 = a0 > a1 ? a0 : a1;
        u32 m23 = a2 > a3 ? a2 : a3;
        u32 m = m01 > m23 ? m01 : m23;
        if (__all((int)(m != SENT))) break;
      }
    }
    __syncthreads();
  };

  auto put_part = [&](const f4* acc) {
#pragma unroll
    for (int t = 0; t < 2; ++t)
#pragma unroll
      for (int r = 0; r < 4; ++r)
        part[(kq * 64 + bt2 * 32 + t * 16 + q * 4 + r) * 17 + c] = acc[t][r];
  };

  auto dec_partial = [&](const u16* __restrict__ h2b) {
    if (ng < 171) {
      const u16* hp = h2b + (size_t)w * 16 * 512 + lane * 8;
      const u16* wp = p.wdec + (size_t)ng * 1024 + w * 128;
      h8 hv[16];
#pragma unroll
      for (int i = 0; i < 16; ++i) hv[i] = *(const h8*)(hp + (size_t)i * 512);
      u32 mx = 0;
#pragma unroll
      for (int i = 0; i < 16; ++i) { u32 s = sentmax(hv[i]); mx = mx > s ? mx : s; }
      if (__builtin_expect(__any((int)(mx == SENT)), 0)) {
        for (;;) {
#pragma unroll
          for (int i = 0; i < 16; ++i) hv[i] = bypass_load(hp + (size_t)i * 512);
          __builtin_amdgcn_s_waitcnt(0x0f70);
          mx = 0;
#pragma unroll
          for (int i = 0; i < 16; ++i) { u32 s = sentmax(hv[i]); mx = mx > s ? mx : s; }
          if (!__any((int)(mx == SENT))) break;
        }
      }
      float s = 0.f;
#pragma unroll
      for (int i = 0; i < 16; ++i) {
        h8 wv8 = *(const h8*)(wp + i * 8);
#pragma unroll
        for (int jj = 0; jj < 8; ++jj) s += (float)hv[i][jj] * (float)wv8[jj];
      }
      decp[w][lane] = s;
    }
  };
  auto dec_reduce = [&](int tout) {  // one wave, lane = batch row
    if (ng < 171) {
      float o = dec_bng;
#pragma unroll
      for (int i = 0; i < 8; ++i) o += decp[i][lane];
      p.out[(size_t)lane * 17100 + (size_t)tout * 171 + ng] = o;
    }
  };

  for (int t = 0; t < 100; ++t) {
    const bool cond = (t % 10) < 5;
    const u16* h0r = p.h0 + (size_t)t * HSZ;  // slot 0 = zeros
    const u16* h1r = p.h1 + (size_t)t * HSZ;
    const u16* h2r = p.h2 + (size_t)t * HSZ;
    u16* h0w = p.h0 + (size_t)(t + 1) * HSZ;
    u16* h1w = p.h1 + (size_t)(t + 1) * HSZ;
    u16* h2w = p.h2 + (size_t)(t + 1) * HSZ;

    // ---- window A: layer 1 ----
    {
      f4 acc[2] = {{0, 0, 0, 0}, {0, 0, 0, 0}};
      gemm_hreg<8>(acc, h0r, r_w1h, kq, bt2, q, c);   // stale (verified)
      if (cond) {
        gemm_fr(acc, p.fr + (size_t)t * 64 * 192, r_w1x, kq, bt2, q, c);
        __syncthreads();   // part[] rendezvous only: no fresh operand
      } else {
        canary_wait(h2r);                             // h2(t-1) arrives
        gemm_hreg<8>(acc, h2r, r_weff, kq, bt2, q, c);
      }
      put_part(acc);
      __syncthreads();
      if (w == 0) combine_pub(cr0, cond ? rb_r : rb_a, h0w);
    }
    // ---- window B: layer 2 ----
    {
      f4 acc[2] = {{0, 0, 0, 0}, {0, 0, 0, 0}};
      gemm_hlds(acc, h1r, lds_w2, 32, kq, bt2, q, c, lane);  // stale hh-half
      canary_wait(h0w);                                      // h0(t) arrives
      gemm_hlds(acc, h0w, lds_w2, 0, kq, bt2, q, c, lane);   // fresh ih-half
      put_part(acc);
      __syncthreads();
      if (w == 0) combine_pub(cr1, rb2, h1w);
    }
    // ---- window C: layer 3 (+ decoder for t-1, stale h2) ----
    {
      f4 acc[2] = {{0, 0, 0, 0}, {0, 0, 0, 0}};
      gemm_hlds(acc, h2r, lds_w3, 32, kq, bt2, q, c, lane);  // stale hh-half
      if (t > 0) dec_partial(h2r);                           // stale (verified)
      canary_wait(h1w);                                      // h1(t) arrives
      gemm_hlds(acc, h1w, lds_w3, 0, kq, bt2, q, c, lane);   // fresh ih-half
      put_part(acc);
      __syncthreads();
      if (w == 0) combine_pub(cr2, rb3, h2w);
      else if (w == 1 && t > 0) dec_reduce(t - 1);
    }
  }
  // final decoder: out(99) from h2 slot 100
  canary_wait(p.h2 + (size_t)100 * HSZ);
  dec_partial(p.h2 + (size_t)100 * HSZ);
  __syncthreads();
  if (w == 0) dec_reduce(99);
}

// ------------------------- prep kernels -------------------------

// Pack [4096 x (KA+KB)] fp32 weights (two halves) into MFMA-B fragments:
// dst[((ng*nkt + kt)*64 + lane)*8 + j] = W[row(c)][kt*32 + (lane>>4)*8 + j]
// row(c) = (c>>2)*1024 + ng*4 + (c&3).  Zero-pads k >= KA+KB.
__global__ void pack_w_kernel(const float* __restrict__ srcA, int KA,
                              const float* __restrict__ srcB, int KB,
                              u16* __restrict__ dst, int nkt) {
  int blk = blockIdx.x;
  int ng = blk / nkt, kt = blk % nkt;
  int lane = threadIdx.x;
  int c = lane & 15, q = lane >> 4;
  int row = (c >> 2) * 1024 + ng * 4 + (c & 3);
  int k0 = kt * 32 + q * 8;
  alignas(16) u16 outv[8];
  for (int j = 0; j < 8; ++j) {
    int k = k0 + j;
    float v = 0.f;
    if (k < KA) v = srcA[(size_t)row * KA + k];
    else if (k - KA < KB) v = srcB[(size_t)row * KB + (k - KA)];
    f16 hv = (f16)v;
    outv[j] = *(u16*)&hv;
  }
  *(uint4*)(dst + ((size_t)blk * 64 + lane) * 8) = *(const uint4*)outv;
}

// W_eff[n][k] = sum_{r<171} w_ih1[n][r] * dec_w[r][k], MFMA-B packed fp16.
__global__ void pack_weff_kernel(const float* __restrict__ w_ih1,
                                 const float* __restrict__ dec_w, u16* __restrict__ dst) {
  int blk = blockIdx.x;  // ng*32 + kt
  int ng = blk >> 5, kt = blk & 31;
  int lane = threadIdx.x;
  int c = lane & 15, q = lane >> 4;
  int row = (c >> 2) * 1024 + ng * 4 + (c & 3);
  int k0 = kt * 32 + q * 8;
  float acc[8] = {0.f, 0.f, 0.f, 0.f, 0.f, 0.f, 0.f, 0.f};
  for (int r = 0; r < 171; ++r) {
    float wi = w_ih1[(size_t)row * 171 + r];
    const float* dw = dec_w + (size_t)r * 1024 + k0;
#pragma unroll
    for (int j = 0; j < 8; ++j) acc[j] += wi * dw[j];
  }
  alignas(16) u16 outv[8];
  for (int j = 0; j < 8; ++j) { f16 hv = (f16)acc[j]; outv[j] = *(u16*)&hv; }
  *(uint4*)(dst + ((size_t)blk * 64 + lane) * 8) = *(const uint4*)outv;
}

__global__ void prep_bias_kernel(const float* b_ih1, const float* b_hh1,
                                 const float* w_ih1, const float* dec_b,
                                 const float* b_ih2, const float* b_hh2,
                                 const float* b_ih3, const float* b_hh3,
                                 float* br, float* ba, float* b2, float* b3) {
  int n = blockIdx.x * 256 + threadIdx.x;  // 0..4095
  float s = b_ih1[n] + b_hh1[n];
  br[n] = s;
  float a = 0.f;
  for (int r = 0; r < 171; ++r) a += w_ih1[(size_t)n * 171 + r] * dec_b[r];
  ba[n] = s + a;  // autoregressive path: + W_ih1 @ dec_b
  b2[n] = b_ih2[n] + b_hh2[n];
  b3[n] = b_ih3[n] + b_hh3[n];
}

// real_seq [64][100][171] fp32 -> fr16 [100][64][192] fp16 (zero-padded K)
__global__ void pack_frames_kernel(const float* __restrict__ rs, u16* __restrict__ fr) {
  int i = blockIdx.x * 256 + threadIdx.x;
  int j = i % 192;
  int tb = i / 192;
  int b = tb % 64, t = tb / 64;
  float v = (j < 171) ? rs[((size_t)b * 100 + t) * 171 + j] : 0.f;
  f16 hv = (f16)v;
  fr[i] = *(u16*)&hv;
}

__global__ void pack_wdec_kernel(const float* __restrict__ dw, u16* __restrict__ dst) {
  int i = blockIdx.x * 256 + threadIdx.x;
  if (i < 171 * 1024) { f16 hv = (f16)dw[i]; dst[i] = *(u16*)&hv; }
}

// h slot 0 = real zeros (initial state); slots 1..100 = sentinel 0xFFFFFFFF.
// Kernel-end writeback/invalidate makes these globally visible before
// lstm_main launches (same stream).
__global__ void init_kernel(u32* h0, u32* h1, u32* h2) {
  int i = blockIdx.x * 256 + threadIdx.x;   // 0 .. 101*32768-1
  const int SLOT = 32768;                   // u32 per h slot
  u32 v = (i < SLOT) ? 0u : SENT;
  h0[i] = v; h1[i] = v; h2[i] = v;
}

extern "C" void kernel_launch(void* const* d_in, const int* in_sizes, int n_in,
                              void* d_out, int out_size, void* d_ws, size_t ws_size,
                              hipStream_t stream) {
  const float* real_seq = (const float*)d_in[0];
  const float* w_ih1 = (const float*)d_in[1];
  const float* w_hh1 = (const float*)d_in[2];
  const float* b_ih1 = (const float*)d_in[3];
  const float* b_hh1 = (const float*)d_in[4];
  const float* w_ih2 = (const float*)d_in[5];
  const float* w_hh2 = (const float*)d_in[6];
  const float* b_ih2 = (const float*)d_in[7];
  const float* b_hh2 = (const float*)d_in[8];
  const float* w_ih3 = (const float*)d_in[9];
  const float* w_hh3 = (const float*)d_in[10];
  const float* b_ih3 = (const float*)d_in[11];
  const float* b_hh3 = (const float*)d_in[12];
  const float* dec_w = (const float*)d_in[13];
  const float* dec_b = (const float*)d_in[14];

  char* ws = (char*)d_ws;
  size_t off = 0;
  auto alloc = [&](size_t bytes) {
    char* pp = ws + off;
    off += (bytes + 255) & ~(size_t)255;
    return pp;
  };
  u16* w1h  = (u16*)alloc(256ULL * 32 * 512 * 2);   // w_hh1 packed
  u16* weff = (u16*)alloc(256ULL * 32 * 512 * 2);   // W_ih1 @ dec_w packed
  u16* w1x  = (u16*)alloc(256ULL * 6 * 512 * 2);    // w_ih1 packed (K padded 192)
  u16* w2   = (u16*)alloc(256ULL * 64 * 512 * 2);   // [w_ih2 | w_hh2] packed
  u16* w3   = (u16*)alloc(256ULL * 64 * 512 * 2);   // [w_ih3 | w_hh3] packed
  u16* wdec = (u16*)alloc(171ULL * 1024 * 2);       // dec_w fp16 row-major
  u16* fr   = (u16*)alloc(100ULL * 64 * 192 * 2);   // frames fp16 padded
  u16* h0   = (u16*)alloc(101ULL * HSZ * 2);        // rotating h, [k/8][b][8]
  u16* h1   = (u16*)alloc(101ULL * HSZ * 2);
  u16* h2   = (u16*)alloc(101ULL * HSZ * 2);
  float* br  = (float*)alloc(4096 * 4);
  float* ba  = (float*)alloc(4096 * 4);
  float* b2s = (float*)alloc(4096 * 4);
  float* b3s = (float*)alloc(4096 * 4);
  (void)ws_size; (void)in_sizes; (void)n_in; (void)out_size;  // needs ~91 MiB ws

  pack_w_kernel<<<256 * 32, 64, 0, stream>>>(w_hh1, 1024, nullptr, 0, w1h, 32);
  pack_w_kernel<<<256 * 6, 64, 0, stream>>>(w_ih1, 171, nullptr, 0, w1x, 6);
  pack_w_kernel<<<256 * 64, 64, 0, stream>>>(w_ih2, 1024, w_hh2, 1024, w2, 64);
  pack_w_kernel<<<256 * 64, 64, 0, stream>>>(w_ih3, 1024, w_hh3, 1024, w3, 64);
  pack_weff_kernel<<<256 * 32, 64, 0, stream>>>(w_ih1, dec_w, weff);
  pack_wdec_kernel<<<(171 * 1024 + 255) / 256, 256, 0, stream>>>(dec_w, wdec);
  pack_frames_kernel<<<100 * 64 * 192 / 256, 256, 0, stream>>>(real_seq, fr);
  prep_bias_kernel<<<16, 256, 0, stream>>>(b_ih1, b_hh1, w_ih1, dec_b,
                                           b_ih2, b_hh2, b_ih3, b_hh3, br, ba, b2s, b3s);
  init_kernel<<<101 * 32768 / 256, 256, 0, stream>>>((u32*)h0, (u32*)h1, (u32*)h2);

  P p{w1h, weff, w1x, w2, w3, wdec, fr, br, ba, b2s, b3s, dec_b,
      h0, h1, h2, (float*)d_out};
  lstm_main<<<256, 512, 0, stream>>>(p);
}

// Round 4
// 1689.152 us; speedup vs baseline: 1.6638x; 1.0387x over previous
//
#include <hip/hip_runtime.h>
#include <hip/hip_fp16.h>

// Persistent-kernel autoregressive LSTM for MI355X (gfx950).  Round 9.
//
// R8 post-mortem (NaN): (a) inline-asm loads + separate builtin waitcnt let
// the compiler hoist sentinel checks above the wait (guide rule #18) -> poll
// exits on garbage; (b) all-bypass fresh fetch killed the 32x per-XCD L2
// amortization R7's FETCH_SIZE (203MB vs 9.6GB logical) proves exists.
// R9 = R7 protocol restored (canary detect + L2-amortized plain fetch +
// verify backstop; measured 1513us) plus:
//  (1) sched_barrier(0) after every asm-load waitcnt (rule #18 hardening);
//  (2) cond-timestep A-window hoisting: A(t+1) has no fresh operand when
//      cond(t+1), so its gemm+combine+publish runs at the tail of window
//      B(t), hidden under h1(t)'s store flight.  49 of 300 serial windows
//      vanish; h0(t+1) pre-arrives for B(t+1)'s detect.
//  (3) s_setprio(1) around the combine (1 combine wave vs 7 parked).

typedef unsigned short u16;
typedef unsigned int u32;
typedef _Float16 f16;
typedef _Float16 h8 __attribute__((ext_vector_type(8)));
typedef float f4 __attribute__((ext_vector_type(4)));
typedef u32 u32x4 __attribute__((ext_vector_type(4)));
typedef u32 u32x2 __attribute__((ext_vector_type(2)));

#define HSZ 65536  // halves per h slot: layout [128 kgrp][64 b][8 u]
#define SENT 0xFFFFFFFFu

static __device__ __forceinline__ f4 mfma16(h8 a, h8 b, f4 c) {
  return __builtin_amdgcn_mfma_f32_16x16x32_f16(a, b, c, 0, 0, 0);
}

static __device__ __forceinline__ float fsig(float x) {
  return 1.f / (1.f + __expf(-x));
}
// overflow-safe: x->+inf => 1, x->-inf => -1 (no inf/inf NaN)
static __device__ __forceinline__ float ftanh(float x) {
  return 1.f - 2.f / (1.f + __expf(2.f * x));
}

// max of the 4 dwords of a fragment: == SENT iff any dword is the sentinel.
static __device__ __forceinline__ u32 sentmax(h8 v) {
  union { h8 h; u32x4 u; } cv; cv.h = v;
  u32 a = cv.u.x > cv.u.y ? cv.u.x : cv.u.y;
  u32 b = cv.u.z > cv.u.w ? cv.u.z : cv.u.w;
  return a > b ? a : b;
}

static __device__ __forceinline__ h8 bypass_load(const u16* p) {
  u32x4 v;
  asm volatile("global_load_dwordx4 %0, %1, off sc0 sc1"
               : "=v"(v) : "v"(p) : "memory");
  union { u32x4 u; h8 h; } cv; cv.u = v;
  return cv.h;
}

// rule #18: drain vmcnt AND fence the scheduler so register-only checks of
// inline-asm load results cannot be hoisted above the wait.
static __device__ __forceinline__ void vm_drain_fence() {
  __builtin_amdgcn_s_waitcnt(0x0f70);     // vmcnt(0)
  __builtin_amdgcn_sched_barrier(0);
}

struct P {
  const u16 *w1h, *weff, *w1x, *w2, *w3, *wdec, *fr;
  const float *br, *ba, *b2s, *b3s, *dec_b;
  u16 *h0, *h1, *h2;
  float* out;
};

// A-frag (16x32 tile): lane(q=lane>>4, c=lane&15) holds A[m=c][k=q*8+j].
// h element [b][k] lives at [(k>>3)*512 + b*8 + (k&7)] -> one h8 load.
// Wave (kq, bt2) covers K-quarter kq (8 kt) x batch rows [bt2*32, bt2*32+32).
// Plain loads (L2-amortized across the XCD) + grouped verify + rare bypass
// retry.  Used for stale AND post-canary fresh reads.
template<int NJ>
static __device__ __forceinline__ void gemm_hreg(f4* acc, const u16* __restrict__ h,
                                                 const h8 (&wr)[NJ], int kq, int bt2,
                                                 int q, int c) {
  h8 a[NJ * 2];
#pragma unroll
  for (int jj = 0; jj < NJ; ++jj) {
    const u16* hp = h + (size_t)((kq * 8 + jj) * 4 + q) * 512;
#pragma unroll
    for (int t = 0; t < 2; ++t)
      a[jj * 2 + t] = *(const h8*)(hp + ((bt2 * 2 + t) * 16 + c) * 8);
  }
  u32 mx = 0;
#pragma unroll
  for (int i = 0; i < NJ * 2; ++i) { u32 s = sentmax(a[i]); mx = mx > s ? mx : s; }
  if (__builtin_expect(__any((int)(mx == SENT)), 0)) {
    for (;;) {
#pragma unroll
      for (int jj = 0; jj < NJ; ++jj) {
        const u16* hp = h + (size_t)((kq * 8 + jj) * 4 + q) * 512;
#pragma unroll
        for (int t = 0; t < 2; ++t)
          a[jj * 2 + t] = bypass_load(hp + ((bt2 * 2 + t) * 16 + c) * 8);
      }
      vm_drain_fence();
      mx = 0;
#pragma unroll
      for (int i = 0; i < NJ * 2; ++i) { u32 s = sentmax(a[i]); mx = mx > s ? mx : s; }
      if (!__any((int)(mx == SENT))) break;
    }
  }
#pragma unroll
  for (int jj = 0; jj < NJ; ++jj)
#pragma unroll
    for (int t = 0; t < 2; ++t)
      acc[t] = mfma16(a[jj * 2 + t], wr[jj], acc[t]);
}

// Same, weights from LDS (w2/w3), kt offset by ktbase.
static __device__ __forceinline__ void gemm_hlds(f4* acc, const u16* __restrict__ h,
                                                 const u16* lw, int ktbase, int kq,
                                                 int bt2, int q, int c, int lane) {
  h8 a[16];
#pragma unroll
  for (int jj = 0; jj < 8; ++jj) {
    const u16* hp = h + (size_t)((kq * 8 + jj) * 4 + q) * 512;
#pragma unroll
    for (int t = 0; t < 2; ++t)
      a[jj * 2 + t] = *(const h8*)(hp + ((bt2 * 2 + t) * 16 + c) * 8);
  }
  u32 mx = 0;
#pragma unroll
  for (int i = 0; i < 16; ++i) { u32 s = sentmax(a[i]); mx = mx > s ? mx : s; }
  if (__builtin_expect(__any((int)(mx == SENT)), 0)) {
    for (;;) {
#pragma unroll
      for (int jj = 0; jj < 8; ++jj) {
        const u16* hp = h + (size_t)((kq * 8 + jj) * 4 + q) * 512;
#pragma unroll
        for (int t = 0; t < 2; ++t)
          a[jj * 2 + t] = bypass_load(hp + ((bt2 * 2 + t) * 16 + c) * 8);
      }
      vm_drain_fence();
      mx = 0;
#pragma unroll
      for (int i = 0; i < 16; ++i) { u32 s = sentmax(a[i]); mx = mx > s ? mx : s; }
      if (!__any((int)(mx == SENT))) break;
    }
  }
#pragma unroll
  for (int jj = 0; jj < 8; ++jj) {
    h8 b = *(const h8*)(lw + (size_t)((ktbase + kq * 8 + jj) * 64 + lane) * 8);
    acc[0] = mfma16(a[jj * 2 + 0], b, acc[0]);
    acc[1] = mfma16(a[jj * 2 + 1], b, acc[1]);
  }
}

// Frame input [64][192] row-major; kt in [0,6) mapped kt = kq*2+jj, kq<3.
// Frames are static (never sentinel) -> plain loads, no verify.
static __device__ __forceinline__ void gemm_fr(f4* acc, const u16* __restrict__ frt,
                                               const h8 (&wr)[2], int kq, int bt2,
                                               int q, int c) {
  if (kq < 3) {
#pragma unroll
    for (int jj = 0; jj < 2; ++jj) {
      int kt = kq * 2 + jj;
      h8 b = wr[jj];
#pragma unroll
      for (int t = 0; t < 2; ++t) {
        h8 a = *(const h8*)(frt + (size_t)((bt2 * 2 + t) * 16 + c) * 192 + kt * 32 + q * 8);
        acc[t] = mfma16(a, b, acc[t]);
      }
    }
  }
}

__launch_bounds__(512, 2)
__global__ void lstm_main(P p) {
  const int ng = blockIdx.x;        // unit-group: owns hidden units [4ng, 4ng+4)
  const int tid = threadIdx.x;
  const int lane = tid & 63;
  const int w = tid >> 6;           // 8 waves
  const int kq = w & 3;             // K-quarter
  const int bt2 = w >> 2;           // batch half
  const int c = lane & 15;
  const int q = lane >> 4;

  __shared__ u16 lds_w2[64 * 512];       // 64 KB  [kt][lane][8] B-frags
  __shared__ u16 lds_w3[64 * 512];       // 64 KB
  __shared__ float part[4 * 64 * 17];    // [kq][brow][c pad17]
  __shared__ float decp[8][64];

  // ---- one-time: stage w2/w3 slices into LDS ----
  {
    const uint4* s2 = (const uint4*)(p.w2 + (size_t)ng * 64 * 512);
    const uint4* s3 = (const uint4*)(p.w3 + (size_t)ng * 64 * 512);
    uint4* d2 = (uint4*)lds_w2;
    uint4* d3 = (uint4*)lds_w3;
    for (int i = tid; i < 4096; i += 512) { d2[i] = s2[i]; d3[i] = s3[i]; }
  }

  // ---- one-time: w1h/weff/w1x B-frags into registers (~72 VGPR/wave) ----
  h8 r_w1h[8], r_weff[8], r_w1x[2];
  {
#pragma unroll
    for (int jj = 0; jj < 8; ++jj) {
      r_w1h[jj] = *(const h8*)(p.w1h + (size_t)((ng * 32 + kq * 8 + jj) * 64 + lane) * 8);
      r_weff[jj] = *(const h8*)(p.weff + (size_t)((ng * 32 + kq * 8 + jj) * 64 + lane) * 8);
    }
    if (kq < 3) {
#pragma unroll
      for (int jj = 0; jj < 2; ++jj)
        r_w1x[jj] = *(const h8*)(p.w1x + (size_t)((ng * 6 + kq * 2 + jj) * 64 + lane) * 8);
    }
  }

  // ---- wave-0-only: hoist the 4x16 bias vectors into registers ----
  float rb_r[16], rb_a[16], rb2[16], rb3[16];
  if (w == 0) {
#pragma unroll
    for (int i = 0; i < 16; ++i) {
      int idx = (i >> 2) * 1024 + ng * 4 + (i & 3);
      rb_r[i] = p.br[idx];  rb_a[i] = p.ba[idx];
      rb2[i] = p.b2s[idx];  rb3[i] = p.b3s[idx];
    }
  }
  const float dec_bng = (ng < 171) ? p.dec_b[ng] : 0.f;
  __syncthreads();

  // c-state: wave 0, lane = batch row, 4 units per layer
  float cr0[4] = {0, 0, 0, 0}, cr1[4] = {0, 0, 0, 0}, cr2[4] = {0, 0, 0, 0};

  // wave 0 only: reduce K-partials, nonlin, c-state, publish DATA ONLY
  // (one sc0sc1 dwordx2 per lane; no drain, no flag; arrival IS the signal).
  auto combine_pub = [&](float* crL, const float* rb, u16* hw) {
    __builtin_amdgcn_s_setprio(1);
    u32 pk0 = 0, pk1 = 0;
#pragma unroll
    for (int u = 0; u < 4; ++u) {
      float s0 = rb[0 + u], s1 = rb[4 + u], s2 = rb[8 + u], s3 = rb[12 + u];
#pragma unroll
      for (int kqi = 0; kqi < 4; ++kqi) {
        const float* pp = &part[(kqi * 64 + lane) * 17 + u];
        s0 += pp[0]; s1 += pp[4]; s2 += pp[8]; s3 += pp[12];
      }
      float iv = fsig(s0), fv = fsig(s1), gv = ftanh(s2), ov = fsig(s3);
      float cn = fv * crL[u] + iv * gv;
      crL[u] = cn;
      f16 hh = (f16)(ov * ftanh(cn));
      u32 bits = (u32)*(const u16*)&hh;
      if (u < 2) pk0 |= bits << (16 * u); else pk1 |= bits << (16 * (u - 2));
    }
    // h[b][4ng+u]: u32 base (ng>>1)*256 + b*4 + (ng&1)*2; one 8B store.
    u32* dst = (u32*)hw + (size_t)(ng >> 1) * 256 + lane * 4 + (ng & 1) * 2;
    u32x2 pk; pk.x = pk0; pk.y = pk1;
    asm volatile("global_store_dwordx2 %0, %1, off sc0 sc1"
                 : : "v"(dst), "v"(pk) : "memory");
    __builtin_amdgcn_s_setprio(0);
  };

  // wave 1 bypass-polls one 16B canary (batch-row-0 units) per 1KB region of
  // the slot (128 regions; lane covers 2).  Data arrival IS the publish signal.
  auto canary_wait = [&](const u16* slot) {
    if (w == 1) {
      const u32* cp = (const u32*)slot + (size_t)lane * 512;
      for (;;) {
        u32x4 v0, v1;
        asm volatile("global_load_dwordx4 %0, %2, off sc0 sc1\n\t"
                     "global_load_dwordx4 %1, %3, off sc0 sc1"
                     : "=v"(v0), "=v"(v1) : "v"(cp), "v"(cp + 256) : "memory");
        vm_drain_fence();
        u32 a0 = v0.x > v0.y ? v0.x : v0.y;
        u32 a1 = v0.z > v0.w ? v0.z : v0.w;
        u32 a2 = v1.x > v1.y ? v1.x : v1.y;
        u32 a3 = v1.z > v1.w ? v1.z : v1.w;
        u32 m01 = a0 > a1 ? a0 : a1;
        u32 m23 = a2 > a3 ? a2 : a3;
        u32 m = m01 > m23 ? m01 : m23;
        if (__all((int)(m != SENT))) break;
      }
    }
    __syncthreads();
  };

  auto put_part = [&](const f4* acc) {
#pragma unroll
    for (int t = 0; t < 2; ++t)
#pragma unroll
      for (int r = 0; r < 4; ++r)
        part[(kq * 64 + bt2 * 32 + t * 16 + q * 4 + r) * 17 + c] = acc[t][r];
  };

  auto dec_partial = [&](const u16* __restrict__ h2b) {
    if (ng < 171) {
      const u16* hp = h2b + (size_t)w * 16 * 512 + lane * 8;
      const u16* wp = p.wdec + (size_t)ng * 1024 + w * 128;
      h8 hv[16];
#pragma unroll
      for (int i = 0; i < 16; ++i) hv[i] = *(const h8*)(hp + (size_t)i * 512);
      u32 mx = 0;
#pragma unroll
      for (int i = 0; i < 16; ++i) { u32 s = sentmax(hv[i]); mx = mx > s ? mx : s; }
      if (__builtin_expect(__any((int)(mx == SENT)), 0)) {
        for (;;) {
#pragma unroll
          for (int i = 0; i < 16; ++i) hv[i] = bypass_load(hp + (size_t)i * 512);
          vm_drain_fence();
          mx = 0;
#pragma unroll
          for (int i = 0; i < 16; ++i) { u32 s = sentmax(hv[i]); mx = mx > s ? mx : s; }
          if (!__any((int)(mx == SENT))) break;
        }
      }
      float s = 0.f;
#pragma unroll
      for (int i = 0; i < 16; ++i) {
        h8 wv8 = *(const h8*)(wp + i * 8);
#pragma unroll
        for (int jj = 0; jj < 8; ++jj) s += (float)hv[i][jj] * (float)wv8[jj];
      }
      decp[w][lane] = s;
    }
  };
  auto dec_reduce = [&](int tout) {  // one wave, lane = batch row
    if (ng < 171) {
      float o = dec_bng;
#pragma unroll
      for (int i = 0; i < 8; ++i) o += decp[i][lane];
      p.out[(size_t)lane * 17100 + (size_t)tout * 171 + ng] = o;
    }
  };

  for (int t = 0; t < 100; ++t) {
    const bool cond = (t % 10) < 5;
    const bool hoisted = cond && (t > 0);     // A(t) already ran at B(t-1)
    const u16* h0r = p.h0 + (size_t)t * HSZ;  // slot 0 = zeros
    const u16* h1r = p.h1 + (size_t)t * HSZ;
    const u16* h2r = p.h2 + (size_t)t * HSZ;
    u16* h0w = p.h0 + (size_t)(t + 1) * HSZ;
    u16* h1w = p.h1 + (size_t)(t + 1) * HSZ;
    u16* h2w = p.h2 + (size_t)(t + 1) * HSZ;

    // ---- window A: layer 1 (skipped when hoisted into B(t-1)) ----
    if (!hoisted) {
      f4 acc[2] = {{0, 0, 0, 0}, {0, 0, 0, 0}};
      gemm_hreg<8>(acc, h0r, r_w1h, kq, bt2, q, c);   // stale (verified)
      if (cond) {   // only t=0
        gemm_fr(acc, p.fr + (size_t)t * 64 * 192, r_w1x, kq, bt2, q, c);
        __syncthreads();   // part[] rendezvous only: no fresh operand
      } else {
        canary_wait(h2r);                             // h2(t-1) arrives
        gemm_hreg<8>(acc, h2r, r_weff, kq, bt2, q, c);
      }
      put_part(acc);
      __syncthreads();
      if (w == 0) combine_pub(cr0, cond ? rb_r : rb_a, h0w);
    }
    // ---- window B: layer 2 (+ hoisted A(t+1) when cond(t+1)) ----
    {
      f4 acc[2] = {{0, 0, 0, 0}, {0, 0, 0, 0}};
      gemm_hlds(acc, h1r, lds_w2, 32, kq, bt2, q, c, lane);  // stale hh-half
      canary_wait(h0w);                                      // h0(t) arrives
      gemm_hlds(acc, h0w, lds_w2, 0, kq, bt2, q, c, lane);   // fresh ih-half
      put_part(acc);
      __syncthreads();
      if (w == 0) combine_pub(cr1, rb2, h1w);
      if ((t + 1 < 100) && (((t + 1) % 10) < 5)) {
        // A(t+1): inputs are frame(t+1) (static) and h0(t) = slot t+1 (the
        // lines this wave just verified-read; L1/L2-hot).  Runs while h1(t)
        // is in flight; h0(t+1) publishes ~one window early.
        f4 accA[2] = {{0, 0, 0, 0}, {0, 0, 0, 0}};
        gemm_hreg<8>(accA, h0w, r_w1h, kq, bt2, q, c);
        gemm_fr(accA, p.fr + (size_t)(t + 1) * 64 * 192, r_w1x, kq, bt2, q, c);
        __syncthreads();   // combineB's part[] reads are done (wave 0 arrives after)
        put_part(accA);
        __syncthreads();
        if (w == 0) combine_pub(cr0, rb_r, p.h0 + (size_t)(t + 2) * HSZ);
      }
    }
    // ---- window C: layer 3 (+ decoder for t-1, stale h2) ----
    {
      f4 acc[2] = {{0, 0, 0, 0}, {0, 0, 0, 0}};
      gemm_hlds(acc, h2r, lds_w3, 32, kq, bt2, q, c, lane);  // stale hh-half
      if (t > 0) dec_partial(h2r);                           // stale (verified)
      canary_wait(h1w);                                      // h1(t) arrives
      gemm_hlds(acc, h1w, lds_w3, 0, kq, bt2, q, c, lane);   // fresh ih-half
      put_part(acc);
      __syncthreads();
      if (w == 0) combine_pub(cr2, rb3, h2w);
      else if (w == 1 && t > 0) dec_reduce(t - 1);
    }
  }
  // final decoder: out(99) from h2 slot 100
  canary_wait(p.h2 + (size_t)100 * HSZ);
  dec_partial(p.h2 + (size_t)100 * HSZ);
  __syncthreads();
  if (w == 0) dec_reduce(99);
}

// ------------------------- prep kernels -------------------------

// Pack [4096 x (KA+KB)] fp32 weights (two halves) into MFMA-B fragments:
// dst[((ng*nkt + kt)*64 + lane)*8 + j] = W[row(c)][kt*32 + (lane>>4)*8 + j]
// row(c) = (c>>2)*1024 + ng*4 + (c&3).  Zero-pads k >= KA+KB.
__global__ void pack_w_kernel(const float* __restrict__ srcA, int KA,
                              const float* __restrict__ srcB, int KB,
                              u16* __restrict__ dst, int nkt) {
  int blk = blockIdx.x;
  int ng = blk / nkt, kt = blk % nkt;
  int lane = threadIdx.x;
  int c = lane & 15, q = lane >> 4;
  int row = (c >> 2) * 1024 + ng * 4 + (c & 3);
  int k0 = kt * 32 + q * 8;
  alignas(16) u16 outv[8];
  for (int j = 0; j < 8; ++j) {
    int k = k0 + j;
    float v = 0.f;
    if (k < KA) v = srcA[(size_t)row * KA + k];
    else if (k - KA < KB) v = srcB[(size_t)row * KB + (k - KA)];
    f16 hv = (f16)v;
    outv[j] = *(u16*)&hv;
  }
  *(uint4*)(dst + ((size_t)blk * 64 + lane) * 8) = *(const uint4*)outv;
}

// W_eff[n][k] = sum_{r<171} w_ih1[n][r] * dec_w[r][k], MFMA-B packed fp16.
__global__ void pack_weff_kernel(const float* __restrict__ w_ih1,
                                 const float* __restrict__ dec_w, u16* __restrict__ dst) {
  int blk = blockIdx.x;  // ng*32 + kt
  int ng = blk >> 5, kt = blk & 31;
  int lane = threadIdx.x;
  int c = lane & 15, q = lane >> 4;
  int row = (c >> 2) * 1024 + ng * 4 + (c & 3);
  int k0 = kt * 32 + q * 8;
  float acc[8] = {0.f, 0.f, 0.f, 0.f, 0.f, 0.f, 0.f, 0.f};
  for (int r = 0; r < 171; ++r) {
    float wi = w_ih1[(size_t)row * 171 + r];
    const float* dw = dec_w + (size_t)r * 1024 + k0;
#pragma unroll
    for (int j = 0; j < 8; ++j) acc[j] += wi * dw[j];
  }
  alignas(16) u16 outv[8];
  for (int j = 0; j < 8; ++j) { f16 hv = (f16)acc[j]; outv[j] = *(u16*)&hv; }
  *(uint4*)(dst + ((size_t)blk * 64 + lane) * 8) = *(const uint4*)outv;
}

__global__ void prep_bias_kernel(const float* b_ih1, const float* b_hh1,
                                 const float* w_ih1, const float* dec_b,
                                 const float* b_ih2, const float* b_hh2,
                                 const float* b_ih3, const float* b_hh3,
                                 float* br, float* ba, float* b2, float* b3) {
  int n = blockIdx.x * 256 + threadIdx.x;  // 0..4095
  float s = b_ih1[n] + b_hh1[n];
  br[n] = s;
  float a = 0.f;
  for (int r = 0; r < 171; ++r) a += w_ih1[(size_t)n * 171 + r] * dec_b[r];
  ba[n] = s + a;  // autoregressive path: + W_ih1 @ dec_b
  b2[n] = b_ih2[n] + b_hh2[n];
  b3[n] = b_ih3[n] + b_hh3[n];
}

// real_seq [64][100][171] fp32 -> fr16 [100][64][192] fp16 (zero-padded K)
__global__ void pack_frames_kernel(const float* __restrict__ rs, u16* __restrict__ fr) {
  int i = blockIdx.x * 256 + threadIdx.x;
  int j = i % 192;
  int tb = i / 192;
  int b = tb % 64, t = tb / 64;
  float v = (j < 171) ? rs[((size_t)b * 100 + t) * 171 + j] : 0.f;
  f16 hv = (f16)v;
  fr[i] = *(u16*)&hv;
}

__global__ void pack_wdec_kernel(const float* __restrict__ dw, u16* __restrict__ dst) {
  int i = blockIdx.x * 256 + threadIdx.x;
  if (i < 171 * 1024) { f16 hv = (f16)dw[i]; dst[i] = *(u16*)&hv; }
}

// h slot 0 = real zeros (initial state); slots 1..100 = sentinel 0xFFFFFFFF.
// Kernel-end writeback makes these globally visible before lstm_main.
__global__ void init_kernel(u32* h0, u32* h1, u32* h2) {
  int i = blockIdx.x * 256 + threadIdx.x;   // 0 .. 101*32768-1
  const int SLOT = 32768;                   // u32 per h slot
  u32 v = (i < SLOT) ? 0u : SENT;
  h0[i] = v; h1[i] = v; h2[i] = v;
}

extern "C" void kernel_launch(void* const* d_in, const int* in_sizes, int n_in,
                              void* d_out, int out_size, void* d_ws, size_t ws_size,
                              hipStream_t stream) {
  const float* real_seq = (const float*)d_in[0];
  const float* w_ih1 = (const float*)d_in[1];
  const float* w_hh1 = (const float*)d_in[2];
  const float* b_ih1 = (const float*)d_in[3];
  const float* b_hh1 = (const float*)d_in[4];
  const float* w_ih2 = (const float*)d_in[5];
  const float* w_hh2 = (const float*)d_in[6];
  const float* b_ih2 = (const float*)d_in[7];
  const float* b_hh2 = (const float*)d_in[8];
  const float* w_ih3 = (const float*)d_in[9];
  const float* w_hh3 = (const float*)d_in[10];
  const float* b_ih3 = (const float*)d_in[11];
  const float* b_hh3 = (const float*)d_in[12];
  const float* dec_w = (const float*)d_in[13];
  const float* dec_b = (const float*)d_in[14];

  char* ws = (char*)d_ws;
  size_t off = 0;
  auto alloc = [&](size_t bytes) {
    char* pp = ws + off;
    off += (bytes + 255) & ~(size_t)255;
    return pp;
  };
  u16* w1h  = (u16*)alloc(256ULL * 32 * 512 * 2);   // w_hh1 packed
  u16* weff = (u16*)alloc(256ULL * 32 * 512 * 2);   // W_ih1 @ dec_w packed
  u16* w1x  = (u16*)alloc(256ULL * 6 * 512 * 2);    // w_ih1 packed (K padded 192)
  u16* w2   = (u16*)alloc(256ULL * 64 * 512 * 2);   // [w_ih2 | w_hh2] packed
  u16* w3   = (u16*)alloc(256ULL * 64 * 512 * 2);   // [w_ih3 | w_hh3] packed
  u16* wdec = (u16*)alloc(171ULL * 1024 * 2);       // dec_w fp16 row-major
  u16* fr   = (u16*)alloc(100ULL * 64 * 192 * 2);   // frames fp16 padded
  u16* h0   = (u16*)alloc(101ULL * HSZ * 2);        // rotating h, [k/8][b][8]
  u16* h1   = (u16*)alloc(101ULL * HSZ * 2);
  u16* h2   = (u16*)alloc(101ULL * HSZ * 2);
  float* br  = (float*)alloc(4096 * 4);
  float* ba  = (float*)alloc(4096 * 4);
  float* b2s = (float*)alloc(4096 * 4);
  float* b3s = (float*)alloc(4096 * 4);
  (void)ws_size; (void)in_sizes; (void)n_in; (void)out_size;  // needs ~91 MiB ws

  pack_w_kernel<<<256 * 32, 64, 0, stream>>>(w_hh1, 1024, nullptr, 0, w1h, 32);
  pack_w_kernel<<<256 * 6, 64, 0, stream>>>(w_ih1, 171, nullptr, 0, w1x, 6);
  pack_w_kernel<<<256 * 64, 64, 0, stream>>>(w_ih2, 1024, w_hh2, 1024, w2, 64);
  pack_w_kernel<<<256 * 64, 64, 0, stream>>>(w_ih3, 1024, w_hh3, 1024, w3, 64);
  pack_weff_kernel<<<256 * 32, 64, 0, stream>>>(w_ih1, dec_w, weff);
  pack_wdec_kernel<<<(171 * 1024 + 255) / 256, 256, 0, stream>>>(dec_w, wdec);
  pack_frames_kernel<<<100 * 64 * 192 / 256, 256, 0, stream>>>(real_seq, fr);
  prep_bias_kernel<<<16, 256, 0, stream>>>(b_ih1, b_hh1, w_ih1, dec_b,
                                           b_ih2, b_hh2, b_ih3, b_hh3, br, ba, b2s, b3s);
  init_kernel<<<101 * 32768 / 256, 256, 0, stream>>>((u32*)h0, (u32*)h1, (u32*)h2);

  P p{w1h, weff, w1x, w2, w3, wdec, fr, br, ba, b2s, b3s, dec_b,
      h0, h1, h2, (float*)d_out};
  lstm_main<<<256, 512, 0, stream>>>(p);
}